// Round 11
// baseline (88.622 us; speedup 1.0000x reference)
//
#include <hip/hip_runtime.h>
#include <hip/hip_bf16.h>
#include <math.h>

// Conditional_Embedding_Contrastive_loss on MI355X (gfx950)
// R8: R7 + double-buffered K-loop (2-phase: stage s+1 issued before compute of s,
//     ONE barrier per K-step). LDS 64KB/block; residency stays 2/CU (block-count-
//     limited), in-block overlap replaces the missing co-residency overlap.

#define NN   4096
#define DD   1024
#define NCLS 1000
#define EPSF 1e-8f
#define MW   (NN / 32)   // 128 mask words per class row
#define NTILE 528        // 32*33/2 upper-tri 128x128 tiles
#define SLOTS 32

typedef short bf16x8 __attribute__((ext_vector_type(8)));
typedef float f32x4  __attribute__((ext_vector_type(4)));

// ---------- kernel 0: bit-pack cls_mask + compact labels (fused) ----------
__global__ __launch_bounds__(256) void k_pack(const int* __restrict__ cmask,
                                              const int* __restrict__ lraw,
                                              unsigned int* __restrict__ mbits,
                                              int* __restrict__ lab) {
  const int b = blockIdx.x;
  if (b < NCLS * MW / 256) {             // 500 pack blocks
    const int wword = b * 256 + threadIdx.x;
    const int* src = cmask + (size_t)wword * 32;
    unsigned int v = 0;
    #pragma unroll
    for (int q = 0; q < 8; ++q) {
      const int4 c = *(const int4*)(src + q * 4);
      v |= (c.x != 0 ? 1u : 0u) << (q * 4 + 0);
      v |= (c.y != 0 ? 1u : 0u) << (q * 4 + 1);
      v |= (c.z != 0 ? 1u : 0u) << (q * 4 + 2);
      v |= (c.w != 0 ? 1u : 0u) << (q * 4 + 3);
    }
    mbits[wword] = v;
  } else {                                // 16 label blocks
    __shared__ int stride_s;
    if (threadIdx.x == 0) {
      int stride = 2;  // assume int64 (little-endian)
      #pragma unroll
      for (int t = 0; t < 8; ++t) {
        int lo = lraw[2 * t], hi = lraw[2 * t + 1];
        if (hi != 0 || (unsigned)lo >= (unsigned)NCLS) { stride = 1; break; }
      }
      stride_s = stride;
    }
    __syncthreads();
    const int i = (b - NCLS * MW / 256) * 256 + threadIdx.x;
    lab[i] = lraw[i * stride_s];
  }
}

// ---------- kernel 1: per-row norms, inst2embed_pos, f32->bf16 pack ----------
__global__ __launch_bounds__(256) void k_rowstats(
    const float* __restrict__ X, const float* __restrict__ A,
    const float* __restrict__ Tp, ushort* __restrict__ Xb,
    float* __restrict__ rnx, float* __restrict__ rnT,
    float* __restrict__ epos, float* __restrict__ out) {
  const int i = blockIdx.x;
  const int t = threadIdx.x;
  const size_t base = (size_t)i * DD + t * 4;
  const float4 xv = *(const float4*)(X + base);
  const float4 av = *(const float4*)(A + base);
  float sxx = xv.x * xv.x + xv.y * xv.y + xv.z * xv.z + xv.w * xv.w;
  float saa = av.x * av.x + av.y * av.y + av.z * av.z + av.w * av.w;
  float sxa = xv.x * av.x + xv.y * av.y + xv.z * av.z + xv.w * av.w;

  ushort4 pk;
  { __hip_bfloat16 b;
    b = __float2bfloat16(xv.x); pk.x = *(const ushort*)&b;
    b = __float2bfloat16(xv.y); pk.y = *(const ushort*)&b;
    b = __float2bfloat16(xv.z); pk.z = *(const ushort*)&b;
    b = __float2bfloat16(xv.w); pk.w = *(const ushort*)&b; }
  *(ushort4*)(Xb + base) = pk;

  #pragma unroll
  for (int off = 32; off > 0; off >>= 1) {
    sxx += __shfl_down(sxx, off);
    saa += __shfl_down(saa, off);
    sxa += __shfl_down(sxa, off);
  }
  __shared__ float red[3][4];
  const int w = t >> 6;
  if ((t & 63) == 0) { red[0][w] = sxx; red[1][w] = saa; red[2][w] = sxa; }
  __syncthreads();
  if (t == 0) {
    const float a  = red[0][0] + red[0][1] + red[0][2] + red[0][3];
    const float bb = red[1][0] + red[1][1] + red[1][2] + red[1][3];
    const float c  = red[2][0] + red[2][1] + red[2][2] + red[2][3];
    const float nxi = sqrtf(a), nai = sqrtf(bb);
    const float rT  = 1.0f / Tp[0];
    const float r   = 1.0f / fmaxf(nxi, 1e-20f);
    rnx[i] = r;
    rnT[i] = r * rT;
    epos[i] = expf((c / fmaxf(nxi * nai, EPSF)) * rT);
    if (i == 0) out[0] = 0.f;
  }
}

// ---------- kernel 2: symmetric fused Gram, double-buffered K-loop ----------
#define BM 128
#define BK 64
#define NSTEP (DD / BK)   // 16
// LDS: 2 buffers of ([128][64] bf16 A + B). XOR swizzle phys=log^(row&7),
// pre-swizzled on the GLOBAL source since global_load_lds writes linearly.

__global__ __launch_bounds__(256) void k_gram(
    const ushort* __restrict__ Xb, const float* __restrict__ rnx,
    const float* __restrict__ rnT,
    const int* __restrict__ lab, const unsigned int* __restrict__ mbits,
    float* __restrict__ scrF, float* __restrict__ scrM) {
  __shared__ __align__(16) char As[2][BM * BK * 2];   // 2 x 16 KB
  __shared__ __align__(16) char Bs[2][BM * BK * 2];   // 2 x 16 KB
  const int tid  = threadIdx.x;
  const int lane = tid & 63;
  const int w    = tid >> 6;
  const int wr   = w >> 1, wc = w & 1;

  // triangular decode: tile t -> (by, bx), bx >= by
  const int t = blockIdx.x;
  int a = (int)((sqrtf(8.f * (float)t + 1.f) - 1.f) * 0.5f);
  while ((a + 1) * (a + 2) / 2 <= t) ++a;
  while (a * (a + 1) / 2 > t) --a;
  const int by = t - a * (a + 1) / 2;
  const int bx = a;
  const bool offdiag = (bx != by);
  const int i0 = by * BM;
  const int j0 = bx * BM;

  const int sslot = (lane & 7) ^ (lane >> 3);  // pre-swizzled global k-slot

  f32x4 acc[4][4];
  #pragma unroll
  for (int m = 0; m < 4; ++m)
    #pragma unroll
    for (int n = 0; n < 4; ++n)
      acc[m][n] = (f32x4){0.f, 0.f, 0.f, 0.f};

  const ushort* pA[4];
  const ushort* pB[4];
  #pragma unroll
  for (int q = 0; q < 4; ++q) {
    const int row = q * 32 + w * 8 + (lane >> 3);
    pA[q] = Xb + (size_t)(i0 + row) * DD + sslot * 8;
    pB[q] = Xb + (size_t)(j0 + row) * DD + sslot * 8;
  }

  // prologue: stage step 0 into buffer 0
  #pragma unroll
  for (int q = 0; q < 4; ++q) {
    __builtin_amdgcn_global_load_lds(
        (const __attribute__((address_space(1))) void*)(pA[q]),
        (__attribute__((address_space(3))) void*)(As[0] + (q * 4 + w) * 1024), 16, 0, 0);
    __builtin_amdgcn_global_load_lds(
        (const __attribute__((address_space(1))) void*)(pB[q]),
        (__attribute__((address_space(3))) void*)(Bs[0] + (q * 4 + w) * 1024), 16, 0, 0);
  }
  __syncthreads();

  int cur = 0;
  for (int s = 0; s < NSTEP; ++s) {
    // stage next K-tile into the other buffer (issue-early; barrier at end drains)
    if (s + 1 < NSTEP) {
      const int k0 = (s + 1) * BK;
      #pragma unroll
      for (int q = 0; q < 4; ++q) {
        __builtin_amdgcn_global_load_lds(
            (const __attribute__((address_space(1))) void*)(pA[q] + k0),
            (__attribute__((address_space(3))) void*)(As[cur ^ 1] + (q * 4 + w) * 1024), 16, 0, 0);
        __builtin_amdgcn_global_load_lds(
            (const __attribute__((address_space(1))) void*)(pB[q] + k0),
            (__attribute__((address_space(3))) void*)(Bs[cur ^ 1] + (q * 4 + w) * 1024), 16, 0, 0);
      }
    }
    // compute current buffer
    #pragma unroll
    for (int ks = 0; ks < 2; ++ks) {
      const int slot = ((ks << 2) + (lane >> 4)) ^ (lane & 7);
      bf16x8 af[4], bfr[4];
      #pragma unroll
      for (int m = 0; m < 4; ++m) {
        const int r = (wr << 6) + (m << 4) + (lane & 15);
        af[m] = *(const bf16x8*)(As[cur] + r * 128 + (slot << 4));
      }
      #pragma unroll
      for (int n = 0; n < 4; ++n) {
        const int r = (wc << 6) + (n << 4) + (lane & 15);
        bfr[n] = *(const bf16x8*)(Bs[cur] + r * 128 + (slot << 4));
      }
      #pragma unroll
      for (int m = 0; m < 4; ++m)
        #pragma unroll
        for (int n = 0; n < 4; ++n)
          acc[m][n] = __builtin_amdgcn_mfma_f32_16x16x32_bf16(af[m], bfr[n], acc[m][n], 0, 0, 0);
    }
    __syncthreads();   // drains stage (vmcnt) + ds_reads; buffers swap safely
    cur ^= 1;
  }

  // ---- epilogue (atomic-free). C/D map: col=lane&15, row=(lane>>4)*4+reg.
  // LDS combine buffers reuse As[0] (all K-loop reads retired at last barrier).
  float* LF = (float*)As[0];       // i-side sfull partials, 256 f32
  float* LM = LF + 256;            // i-side smask
  float* GF = LM + 256;            // j-side sfull
  float* GM = GF + 256;            // j-side smask

  float rnT_j[4];
  unsigned long long wj[4];        // mask bits row lab[j_n], i-span of this wave
  #pragma unroll
  for (int n = 0; n < 4; ++n) {
    const int j = j0 + (wc << 6) + (n << 4) + (lane & 15);
    rnT_j[n] = rnT[j];
    wj[n] = *(const unsigned long long*)(mbits + (size_t)lab[j] * MW + (i0 >> 5) + (wr << 1));
  }
  float pse[4] = {0.f, 0.f, 0.f, 0.f}, psm[4] = {0.f, 0.f, 0.f, 0.f};

  #pragma unroll
  for (int m = 0; m < 4; ++m) {
    #pragma unroll
    for (int r = 0; r < 4; ++r) {
      const int irow = (m << 4) + ((lane >> 4) << 2) + r;    // local row in wave's 64-span
      const int i = i0 + (wr << 6) + irow;
      const float rni = rnx[i];
      const unsigned long long wi =
          *(const unsigned long long*)(mbits + (size_t)lab[i] * MW + (j0 >> 5) + (wc << 1));
      float se = 0.f, sm = 0.f;
      #pragma unroll
      for (int n = 0; n < 4; ++n) {
        const int j = j0 + (wc << 6) + (n << 4) + (lane & 15);
        float e = __expf(acc[m][n][r] * rni * rnT_j[n]);
        if (i == j) e = 0.f;                                 // remove_diag
        se += e;
        const int bposj = (n << 4) + (lane & 15);            // j within wave's col-span
        sm += ((wi >> bposj) & 1ull) ? e : 0.f;
        pse[n] += e;
        psm[n] += ((wj[n] >> irow) & 1ull) ? e : 0.f;
      }
      #pragma unroll
      for (int off = 1; off < 16; off <<= 1) {
        se += __shfl_xor(se, off);
        sm += __shfl_xor(sm, off);
      }
      if ((lane & 15) == 0) {                                // lanes 0,16,32,48
        LF[(wc << 7) + (wr << 6) + irow] = se;
        LM[(wc << 7) + (wr << 6) + irow] = sm;
      }
    }
  }
  if (offdiag) {
    #pragma unroll
    for (int n = 0; n < 4; ++n) {
      float se = pse[n], sm = psm[n];
      se += __shfl_xor(se, 16); se += __shfl_xor(se, 32);
      sm += __shfl_xor(sm, 16); sm += __shfl_xor(sm, 32);
      if (lane < 16) {
        GF[(wr << 7) + (wc << 6) + (n << 4) + lane] = se;
        GM[(wr << 7) + (wc << 6) + (n << 4) + lane] = sm;
      }
    }
  }
  __syncthreads();

  // cross-wave combine + coalesced stores. Slot ownership:
  //   i-side (rows i0..i0+127) -> slot bx ; j-side (rows j0..j0+127) -> slot by.
  if (tid < 128) {
    scrF[(size_t)bx * NN + i0 + tid] = LF[tid] + LF[128 + tid];
    if (offdiag) scrF[(size_t)by * NN + j0 + tid] = GF[tid] + GF[128 + tid];
  } else {
    const int u = tid - 128;
    scrM[(size_t)bx * NN + i0 + u] = LM[u] + LM[128 + u];
    if (offdiag) scrM[(size_t)by * NN + j0 + u] = GM[u] + GM[128 + u];
  }
}

// ---------- kernel 3: loss = mean(log(den) - log(num)) ----------
__global__ __launch_bounds__(256) void k_final(
    const float* __restrict__ scrF, const float* __restrict__ scrM,
    const float* __restrict__ epos, float* __restrict__ out) {
  const int idx = blockIdx.x * 256 + threadIdx.x;
  float sf = 0.f, sm = 0.f;
  #pragma unroll
  for (int s = 0; s < SLOTS; ++s) {
    sf += scrF[(size_t)s * NN + idx];
    sm += scrM[(size_t)s * NN + idx];
  }
  const float ep  = epos[idx];
  const float num = sm + ep;
  const float den = ep + sf;
  float v = (logf(den) - logf(num)) * (1.0f / (float)NN);
  #pragma unroll
  for (int off = 32; off > 0; off >>= 1) v += __shfl_down(v, off);
  __shared__ float red[4];
  if ((threadIdx.x & 63) == 0) red[threadIdx.x >> 6] = v;
  __syncthreads();
  if (threadIdx.x == 0) atomicAdd(out, red[0] + red[1] + red[2] + red[3]);
}

extern "C" void kernel_launch(void* const* d_in, const int* in_sizes, int n_in,
                              void* d_out, int out_size, void* d_ws, size_t ws_size,
                              hipStream_t stream) {
  const float* X     = (const float*)d_in[0];
  const float* A     = (const float*)d_in[1];
  const int*   cmask = (const int*)d_in[2];
  const int*   lraw  = (const int*)d_in[3];
  const float* Tp    = (const float*)d_in[4];
  float* out = (float*)d_out;

  char* ws = (char*)d_ws;
  ushort* Xb   = (ushort*)ws;                          // 8 MB
  float* rnx   = (float*)(ws + (size_t)NN * DD * 2);
  float* rnT   = rnx + NN;
  float* epos  = rnT + NN;
  int*   lab   = (int*)(epos + NN);
  unsigned int* mbits = (unsigned int*)(lab + NN);     // 512 KB
  float* scrF  = (float*)(mbits + (size_t)NCLS * MW);  // 512 KB
  float* scrM  = scrF + (size_t)SLOTS * NN;            // 512 KB

  hipLaunchKernelGGL(k_pack,     dim3(NCLS * MW / 256 + NN / 256), dim3(256), 0, stream, cmask, lraw, mbits, lab);
  hipLaunchKernelGGL(k_rowstats, dim3(NN),    dim3(256), 0, stream, X, A, Tp, Xb, rnx, rnT, epos, out);
  hipLaunchKernelGGL(k_gram,     dim3(NTILE), dim3(256), 0, stream, Xb, rnx, rnT, lab, mbits, scrF, scrM);
  hipLaunchKernelGGL(k_final,    dim3(NN/256), dim3(256), 0, stream, scrF, scrM, epos, out);
}

// Round 12
// 83.515 us; speedup vs baseline: 1.0612x; 1.0612x over previous
//
#include <hip/hip_runtime.h>
#include <hip/hip_bf16.h>
#include <math.h>

// Conditional_Embedding_Contrastive_loss on MI355X (gfx950)
// R9: R7 structure (single-buffer, atomic-free epilogue) + XCD-aware tile map:
//     triangle folded into 16 row-pairs (by,31-by) of 33 tiles; XCD x (=blk%8)
//     owns pairs {2x,2x+1} -> 66 tiles/XCD, 4 A-panels (1MB) L2-resident.

#define NN   4096
#define DD   1024
#define NCLS 1000
#define EPSF 1e-8f
#define MW   (NN / 32)   // 128 mask words per class row
#define NTILE 528        // 32*33/2 upper-tri 128x128 tiles
#define SLOTS 32

typedef short bf16x8 __attribute__((ext_vector_type(8)));
typedef float f32x4  __attribute__((ext_vector_type(4)));

// ---------- kernel 0: bit-pack cls_mask + compact labels (fused) ----------
__global__ __launch_bounds__(256) void k_pack(const int* __restrict__ cmask,
                                              const int* __restrict__ lraw,
                                              unsigned int* __restrict__ mbits,
                                              int* __restrict__ lab) {
  const int b = blockIdx.x;
  if (b < NCLS * MW / 256) {             // 500 pack blocks
    const int wword = b * 256 + threadIdx.x;
    const int* src = cmask + (size_t)wword * 32;
    unsigned int v = 0;
    #pragma unroll
    for (int q = 0; q < 8; ++q) {
      const int4 c = *(const int4*)(src + q * 4);
      v |= (c.x != 0 ? 1u : 0u) << (q * 4 + 0);
      v |= (c.y != 0 ? 1u : 0u) << (q * 4 + 1);
      v |= (c.z != 0 ? 1u : 0u) << (q * 4 + 2);
      v |= (c.w != 0 ? 1u : 0u) << (q * 4 + 3);
    }
    mbits[wword] = v;
  } else {                                // 16 label blocks
    __shared__ int stride_s;
    if (threadIdx.x == 0) {
      int stride = 2;  // assume int64 (little-endian)
      #pragma unroll
      for (int t = 0; t < 8; ++t) {
        int lo = lraw[2 * t], hi = lraw[2 * t + 1];
        if (hi != 0 || (unsigned)lo >= (unsigned)NCLS) { stride = 1; break; }
      }
      stride_s = stride;
    }
    __syncthreads();
    const int i = (b - NCLS * MW / 256) * 256 + threadIdx.x;
    lab[i] = lraw[i * stride_s];
  }
}

// ---------- kernel 1: per-row norms, inst2embed_pos, f32->bf16 pack ----------
__global__ __launch_bounds__(256) void k_rowstats(
    const float* __restrict__ X, const float* __restrict__ A,
    const float* __restrict__ Tp, ushort* __restrict__ Xb,
    float* __restrict__ rnx, float* __restrict__ rnT,
    float* __restrict__ epos, float* __restrict__ out) {
  const int i = blockIdx.x;
  const int t = threadIdx.x;
  const size_t base = (size_t)i * DD + t * 4;
  const float4 xv = *(const float4*)(X + base);
  const float4 av = *(const float4*)(A + base);
  float sxx = xv.x * xv.x + xv.y * xv.y + xv.z * xv.z + xv.w * xv.w;
  float saa = av.x * av.x + av.y * av.y + av.z * av.z + av.w * av.w;
  float sxa = xv.x * av.x + xv.y * av.y + xv.z * av.z + xv.w * av.w;

  ushort4 pk;
  { __hip_bfloat16 b;
    b = __float2bfloat16(xv.x); pk.x = *(const ushort*)&b;
    b = __float2bfloat16(xv.y); pk.y = *(const ushort*)&b;
    b = __float2bfloat16(xv.z); pk.z = *(const ushort*)&b;
    b = __float2bfloat16(xv.w); pk.w = *(const ushort*)&b; }
  *(ushort4*)(Xb + base) = pk;

  #pragma unroll
  for (int off = 32; off > 0; off >>= 1) {
    sxx += __shfl_down(sxx, off);
    saa += __shfl_down(saa, off);
    sxa += __shfl_down(sxa, off);
  }
  __shared__ float red[3][4];
  const int w = t >> 6;
  if ((t & 63) == 0) { red[0][w] = sxx; red[1][w] = saa; red[2][w] = sxa; }
  __syncthreads();
  if (t == 0) {
    const float a  = red[0][0] + red[0][1] + red[0][2] + red[0][3];
    const float bb = red[1][0] + red[1][1] + red[1][2] + red[1][3];
    const float c  = red[2][0] + red[2][1] + red[2][2] + red[2][3];
    const float nxi = sqrtf(a), nai = sqrtf(bb);
    const float rT  = 1.0f / Tp[0];
    const float r   = 1.0f / fmaxf(nxi, 1e-20f);
    rnx[i] = r;
    rnT[i] = r * rT;
    epos[i] = expf((c / fmaxf(nxi * nai, EPSF)) * rT);
    if (i == 0) out[0] = 0.f;
  }
}

// ---------- kernel 2: symmetric fused Gram (128x128 tiles, XCD-local map) ----------
#define BM 128
#define BK 64
// LDS: row-major [128][64] bf16, 8x16B slots/row, XOR swizzle phys=log^(row&7),
// pre-swizzled on the GLOBAL source since global_load_lds writes linearly.

__global__ __launch_bounds__(256) void k_gram(
    const ushort* __restrict__ Xb, const float* __restrict__ rnx,
    const float* __restrict__ rnT,
    const int* __restrict__ lab, const unsigned int* __restrict__ mbits,
    float* __restrict__ scrF, float* __restrict__ scrM) {
  __shared__ __align__(16) char As[BM * BK * 2];   // 16 KB
  __shared__ __align__(16) char Bs[BM * BK * 2];   // 16 KB
  const int tid  = threadIdx.x;
  const int lane = tid & 63;
  const int w    = tid >> 6;
  const int wr   = w >> 1, wc = w & 1;

  // XCD-aware tile decode: xcd = blk%8 owns row-pairs {2x, 2x+1}; each pair
  // p covers rows {p, 31-p} with exactly 33 tiles (32-p in row p, p+1 in row 31-p).
  const int xcd = blockIdx.x & 7;
  const int l   = blockIdx.x >> 3;          // 0..65
  const int p   = (xcd << 1) + (l >= 33);   // pair index
  const int q   = (l >= 33) ? (l - 33) : l; // 0..32 within pair
  int by, bx;
  if (q < 32 - p) { by = p;      bx = p + q; }
  else            { by = 31 - p; bx = 31 - p + (q - (32 - p)); }
  const bool offdiag = (bx != by);
  const int i0 = by * BM;
  const int j0 = bx * BM;

  const int sslot = (lane & 7) ^ (lane >> 3);  // pre-swizzled global k-slot

  f32x4 acc[4][4];
  #pragma unroll
  for (int m = 0; m < 4; ++m)
    #pragma unroll
    for (int n = 0; n < 4; ++n)
      acc[m][n] = (f32x4){0.f, 0.f, 0.f, 0.f};

  const ushort* pA[4];
  const ushort* pB[4];
  #pragma unroll
  for (int q2 = 0; q2 < 4; ++q2) {
    const int row = q2 * 32 + w * 8 + (lane >> 3);
    pA[q2] = Xb + (size_t)(i0 + row) * DD + sslot * 8;
    pB[q2] = Xb + (size_t)(j0 + row) * DD + sslot * 8;
  }

  for (int k0 = 0; k0 < DD; k0 += BK) {
    #pragma unroll
    for (int q2 = 0; q2 < 4; ++q2) {
      __builtin_amdgcn_global_load_lds(
          (const __attribute__((address_space(1))) void*)(pA[q2] + k0),
          (__attribute__((address_space(3))) void*)(As + (q2 * 4 + w) * 1024), 16, 0, 0);
      __builtin_amdgcn_global_load_lds(
          (const __attribute__((address_space(1))) void*)(pB[q2] + k0),
          (__attribute__((address_space(3))) void*)(Bs + (q2 * 4 + w) * 1024), 16, 0, 0);
    }
    __syncthreads();

    #pragma unroll
    for (int ks = 0; ks < 2; ++ks) {
      const int slot = ((ks << 2) + (lane >> 4)) ^ (lane & 7);
      bf16x8 af[4], bfr[4];
      #pragma unroll
      for (int m = 0; m < 4; ++m) {
        const int r = (wr << 6) + (m << 4) + (lane & 15);
        af[m] = *(const bf16x8*)(As + r * 128 + (slot << 4));
      }
      #pragma unroll
      for (int n = 0; n < 4; ++n) {
        const int r = (wc << 6) + (n << 4) + (lane & 15);
        bfr[n] = *(const bf16x8*)(Bs + r * 128 + (slot << 4));
      }
      #pragma unroll
      for (int m = 0; m < 4; ++m)
        #pragma unroll
        for (int n = 0; n < 4; ++n)
          acc[m][n] = __builtin_amdgcn_mfma_f32_16x16x32_bf16(af[m], bfr[n], acc[m][n], 0, 0, 0);
    }
    __syncthreads();
  }

  // ---- epilogue (atomic-free). C/D map: col=lane&15, row=(lane>>4)*4+reg.
  float* LF = (float*)As;          // i-side sfull partials, 256 f32
  float* LM = LF + 256;            // i-side smask
  float* GF = LM + 256;            // j-side sfull
  float* GM = GF + 256;            // j-side smask

  float rnT_j[4];
  unsigned long long wj[4];        // mask bits row lab[j_n], i-span of this wave
  #pragma unroll
  for (int n = 0; n < 4; ++n) {
    const int j = j0 + (wc << 6) + (n << 4) + (lane & 15);
    rnT_j[n] = rnT[j];
    wj[n] = *(const unsigned long long*)(mbits + (size_t)lab[j] * MW + (i0 >> 5) + (wr << 1));
  }
  float pse[4] = {0.f, 0.f, 0.f, 0.f}, psm[4] = {0.f, 0.f, 0.f, 0.f};

  #pragma unroll
  for (int m = 0; m < 4; ++m) {
    #pragma unroll
    for (int r = 0; r < 4; ++r) {
      const int irow = (m << 4) + ((lane >> 4) << 2) + r;    // local row in wave's 64-span
      const int i = i0 + (wr << 6) + irow;
      const float rni = rnx[i];
      const unsigned long long wi =
          *(const unsigned long long*)(mbits + (size_t)lab[i] * MW + (j0 >> 5) + (wc << 1));
      float se = 0.f, sm = 0.f;
      #pragma unroll
      for (int n = 0; n < 4; ++n) {
        const int j = j0 + (wc << 6) + (n << 4) + (lane & 15);
        float e = __expf(acc[m][n][r] * rni * rnT_j[n]);
        if (i == j) e = 0.f;                                 // remove_diag
        se += e;
        const int bposj = (n << 4) + (lane & 15);            // j within wave's col-span
        sm += ((wi >> bposj) & 1ull) ? e : 0.f;
        pse[n] += e;
        psm[n] += ((wj[n] >> irow) & 1ull) ? e : 0.f;
      }
      #pragma unroll
      for (int off = 1; off < 16; off <<= 1) {
        se += __shfl_xor(se, off);
        sm += __shfl_xor(sm, off);
      }
      if ((lane & 15) == 0) {                                // lanes 0,16,32,48
        LF[(wc << 7) + (wr << 6) + irow] = se;
        LM[(wc << 7) + (wr << 6) + irow] = sm;
      }
    }
  }
  if (offdiag) {
    #pragma unroll
    for (int n = 0; n < 4; ++n) {
      float se = pse[n], sm = psm[n];
      se += __shfl_xor(se, 16); se += __shfl_xor(se, 32);
      sm += __shfl_xor(sm, 16); sm += __shfl_xor(sm, 32);
      if (lane < 16) {
        GF[(wr << 7) + (wc << 6) + (n << 4) + lane] = se;
        GM[(wr << 7) + (wc << 6) + (n << 4) + lane] = sm;
      }
    }
  }
  __syncthreads();

  // cross-wave combine + coalesced stores. Slot ownership:
  //   i-side (rows i0..i0+127) -> slot bx ; j-side (rows j0..j0+127) -> slot by.
  if (tid < 128) {
    scrF[(size_t)bx * NN + i0 + tid] = LF[tid] + LF[128 + tid];
    if (offdiag) scrF[(size_t)by * NN + j0 + tid] = GF[tid] + GF[128 + tid];
  } else {
    const int u = tid - 128;
    scrM[(size_t)bx * NN + i0 + u] = LM[u] + LM[128 + u];
    if (offdiag) scrM[(size_t)by * NN + j0 + u] = GM[u] + GM[128 + u];
  }
}

// ---------- kernel 3: loss = mean(log(den) - log(num)) ----------
__global__ __launch_bounds__(256) void k_final(
    const float* __restrict__ scrF, const float* __restrict__ scrM,
    const float* __restrict__ epos, float* __restrict__ out) {
  const int idx = blockIdx.x * 256 + threadIdx.x;
  float sf = 0.f, sm = 0.f;
  #pragma unroll
  for (int s = 0; s < SLOTS; ++s) {
    sf += scrF[(size_t)s * NN + idx];
    sm += scrM[(size_t)s * NN + idx];
  }
  const float ep  = epos[idx];
  const float num = sm + ep;
  const float den = ep + sf;
  float v = (logf(den) - logf(num)) * (1.0f / (float)NN);
  #pragma unroll
  for (int off = 32; off > 0; off >>= 1) v += __shfl_down(v, off);
  __shared__ float red[4];
  if ((threadIdx.x & 63) == 0) red[threadIdx.x >> 6] = v;
  __syncthreads();
  if (threadIdx.x == 0) atomicAdd(out, red[0] + red[1] + red[2] + red[3]);
}

extern "C" void kernel_launch(void* const* d_in, const int* in_sizes, int n_in,
                              void* d_out, int out_size, void* d_ws, size_t ws_size,
                              hipStream_t stream) {
  const float* X     = (const float*)d_in[0];
  const float* A     = (const float*)d_in[1];
  const int*   cmask = (const int*)d_in[2];
  const int*   lraw  = (const int*)d_in[3];
  const float* Tp    = (const float*)d_in[4];
  float* out = (float*)d_out;

  char* ws = (char*)d_ws;
  ushort* Xb   = (ushort*)ws;                          // 8 MB
  float* rnx   = (float*)(ws + (size_t)NN * DD * 2);
  float* rnT   = rnx + NN;
  float* epos  = rnT + NN;
  int*   lab   = (int*)(epos + NN);
  unsigned int* mbits = (unsigned int*)(lab + NN);     // 512 KB
  float* scrF  = (float*)(mbits + (size_t)NCLS * MW);  // 512 KB
  float* scrM  = scrF + (size_t)SLOTS * NN;            // 512 KB

  hipLaunchKernelGGL(k_pack,     dim3(NCLS * MW / 256 + NN / 256), dim3(256), 0, stream, cmask, lraw, mbits, lab);
  hipLaunchKernelGGL(k_rowstats, dim3(NN),    dim3(256), 0, stream, X, A, Tp, Xb, rnx, rnT, epos, out);
  hipLaunchKernelGGL(k_gram,     dim3(NTILE), dim3(256), 0, stream, Xb, rnx, rnT, lab, mbits, scrF, scrM);
  hipLaunchKernelGGL(k_final,    dim3(NN/256), dim3(256), 0, stream, scrF, scrM, epos, out);
}

// Round 13
// 81.259 us; speedup vs baseline: 1.0906x; 1.0278x over previous
//
#include <hip/hip_runtime.h>
#include <hip/hip_bf16.h>
#include <math.h>

// Conditional_Embedding_Contrastive_loss on MI355X (gfx950)
// R10: R9 (XCD tile map, atomic-free epilogue) + BK=128 K-steps:
//      stage A-lo/A-hi/B-lo/B-hi ([128][64] each, 64KB LDS), ONE vmcnt-drain
//      per 128-K -> 8 drains instead of 16. Residency stays 2/CU.

#define NN   4096
#define DD   1024
#define NCLS 1000
#define EPSF 1e-8f
#define MW   (NN / 32)   // 128 mask words per class row
#define NTILE 528        // 32*33/2 upper-tri 128x128 tiles
#define SLOTS 32

typedef short bf16x8 __attribute__((ext_vector_type(8)));
typedef float f32x4  __attribute__((ext_vector_type(4)));

// ---------- kernel 0: bit-pack cls_mask + compact labels (fused) ----------
__global__ __launch_bounds__(256) void k_pack(const int* __restrict__ cmask,
                                              const int* __restrict__ lraw,
                                              unsigned int* __restrict__ mbits,
                                              int* __restrict__ lab) {
  const int b = blockIdx.x;
  if (b < NCLS * MW / 256) {             // 500 pack blocks
    const int wword = b * 256 + threadIdx.x;
    const int* src = cmask + (size_t)wword * 32;
    unsigned int v = 0;
    #pragma unroll
    for (int q = 0; q < 8; ++q) {
      const int4 c = *(const int4*)(src + q * 4);
      v |= (c.x != 0 ? 1u : 0u) << (q * 4 + 0);
      v |= (c.y != 0 ? 1u : 0u) << (q * 4 + 1);
      v |= (c.z != 0 ? 1u : 0u) << (q * 4 + 2);
      v |= (c.w != 0 ? 1u : 0u) << (q * 4 + 3);
    }
    mbits[wword] = v;
  } else {                                // 16 label blocks
    __shared__ int stride_s;
    if (threadIdx.x == 0) {
      int stride = 2;  // assume int64 (little-endian)
      #pragma unroll
      for (int t = 0; t < 8; ++t) {
        int lo = lraw[2 * t], hi = lraw[2 * t + 1];
        if (hi != 0 || (unsigned)lo >= (unsigned)NCLS) { stride = 1; break; }
      }
      stride_s = stride;
    }
    __syncthreads();
    const int i = (b - NCLS * MW / 256) * 256 + threadIdx.x;
    lab[i] = lraw[i * stride_s];
  }
}

// ---------- kernel 1: per-row norms, inst2embed_pos, f32->bf16 pack ----------
__global__ __launch_bounds__(256) void k_rowstats(
    const float* __restrict__ X, const float* __restrict__ A,
    const float* __restrict__ Tp, ushort* __restrict__ Xb,
    float* __restrict__ rnx, float* __restrict__ rnT,
    float* __restrict__ epos, float* __restrict__ out) {
  const int i = blockIdx.x;
  const int t = threadIdx.x;
  const size_t base = (size_t)i * DD + t * 4;
  const float4 xv = *(const float4*)(X + base);
  const float4 av = *(const float4*)(A + base);
  float sxx = xv.x * xv.x + xv.y * xv.y + xv.z * xv.z + xv.w * xv.w;
  float saa = av.x * av.x + av.y * av.y + av.z * av.z + av.w * av.w;
  float sxa = xv.x * av.x + xv.y * av.y + xv.z * av.z + xv.w * av.w;

  ushort4 pk;
  { __hip_bfloat16 b;
    b = __float2bfloat16(xv.x); pk.x = *(const ushort*)&b;
    b = __float2bfloat16(xv.y); pk.y = *(const ushort*)&b;
    b = __float2bfloat16(xv.z); pk.z = *(const ushort*)&b;
    b = __float2bfloat16(xv.w); pk.w = *(const ushort*)&b; }
  *(ushort4*)(Xb + base) = pk;

  #pragma unroll
  for (int off = 32; off > 0; off >>= 1) {
    sxx += __shfl_down(sxx, off);
    saa += __shfl_down(saa, off);
    sxa += __shfl_down(sxa, off);
  }
  __shared__ float red[3][4];
  const int w = t >> 6;
  if ((t & 63) == 0) { red[0][w] = sxx; red[1][w] = saa; red[2][w] = sxa; }
  __syncthreads();
  if (t == 0) {
    const float a  = red[0][0] + red[0][1] + red[0][2] + red[0][3];
    const float bb = red[1][0] + red[1][1] + red[1][2] + red[1][3];
    const float c  = red[2][0] + red[2][1] + red[2][2] + red[2][3];
    const float nxi = sqrtf(a), nai = sqrtf(bb);
    const float rT  = 1.0f / Tp[0];
    const float r   = 1.0f / fmaxf(nxi, 1e-20f);
    rnx[i] = r;
    rnT[i] = r * rT;
    epos[i] = expf((c / fmaxf(nxi * nai, EPSF)) * rT);
    if (i == 0) out[0] = 0.f;
  }
}

// ---------- kernel 2: symmetric fused Gram (128x128 tiles, BK=128) ----------
#define BM 128
#define BK 128
// LDS: 4 sub-buffers [128][64] bf16 (A-lo, A-hi, B-lo, B-hi), 16KB each.
// XOR swizzle within each: phys slot = logical ^ (row&7), pre-swizzled on the
// GLOBAL source since global_load_lds writes linearly.

__global__ __launch_bounds__(256) void k_gram(
    const ushort* __restrict__ Xb, const float* __restrict__ rnx,
    const float* __restrict__ rnT,
    const int* __restrict__ lab, const unsigned int* __restrict__ mbits,
    float* __restrict__ scrF, float* __restrict__ scrM) {
  __shared__ __align__(16) char LDS[4 * BM * 64 * 2];   // 64 KB
  char* As0 = LDS;                 // A k-lo
  char* As1 = LDS + 16384;         // A k-hi
  char* Bs0 = LDS + 32768;         // B k-lo
  char* Bs1 = LDS + 49152;         // B k-hi
  const int tid  = threadIdx.x;
  const int lane = tid & 63;
  const int w    = tid >> 6;
  const int wr   = w >> 1, wc = w & 1;

  // XCD-aware tile decode: xcd = blk%8 owns row-pairs {2x, 2x+1}; each pair
  // p covers rows {p, 31-p} with exactly 33 tiles.
  const int xcd = blockIdx.x & 7;
  const int l   = blockIdx.x >> 3;          // 0..65
  const int p   = (xcd << 1) + (l >= 33);   // pair index
  const int q   = (l >= 33) ? (l - 33) : l; // 0..32 within pair
  int by, bx;
  if (q < 32 - p) { by = p;      bx = p + q; }
  else            { by = 31 - p; bx = 31 - p + (q - (32 - p)); }
  const bool offdiag = (bx != by);
  const int i0 = by * BM;
  const int j0 = bx * BM;

  const int sslot = (lane & 7) ^ (lane >> 3);  // pre-swizzled global k-slot

  f32x4 acc[4][4];
  #pragma unroll
  for (int m = 0; m < 4; ++m)
    #pragma unroll
    for (int n = 0; n < 4; ++n)
      acc[m][n] = (f32x4){0.f, 0.f, 0.f, 0.f};

  const ushort* pA[4];
  const ushort* pB[4];
  #pragma unroll
  for (int q2 = 0; q2 < 4; ++q2) {
    const int row = q2 * 32 + w * 8 + (lane >> 3);
    pA[q2] = Xb + (size_t)(i0 + row) * DD + sslot * 8;
    pB[q2] = Xb + (size_t)(j0 + row) * DD + sslot * 8;
  }

  for (int k0 = 0; k0 < DD; k0 += BK) {
    #pragma unroll
    for (int q2 = 0; q2 < 4; ++q2) {
      const int ldo = (q2 * 4 + w) * 1024;
      __builtin_amdgcn_global_load_lds(
          (const __attribute__((address_space(1))) void*)(pA[q2] + k0),
          (__attribute__((address_space(3))) void*)(As0 + ldo), 16, 0, 0);
      __builtin_amdgcn_global_load_lds(
          (const __attribute__((address_space(1))) void*)(pA[q2] + k0 + 64),
          (__attribute__((address_space(3))) void*)(As1 + ldo), 16, 0, 0);
      __builtin_amdgcn_global_load_lds(
          (const __attribute__((address_space(1))) void*)(pB[q2] + k0),
          (__attribute__((address_space(3))) void*)(Bs0 + ldo), 16, 0, 0);
      __builtin_amdgcn_global_load_lds(
          (const __attribute__((address_space(1))) void*)(pB[q2] + k0 + 64),
          (__attribute__((address_space(3))) void*)(Bs1 + ldo), 16, 0, 0);
    }
    __syncthreads();   // single vmcnt drain per 128-K

    #pragma unroll
    for (int kh = 0; kh < 2; ++kh) {
      const char* Ab = kh ? As1 : As0;
      const char* Bb = kh ? Bs1 : Bs0;
      #pragma unroll
      for (int ks = 0; ks < 2; ++ks) {
        const int slot = ((ks << 2) + (lane >> 4)) ^ (lane & 7);
        bf16x8 af[4], bfr[4];
        #pragma unroll
        for (int m = 0; m < 4; ++m) {
          const int r = (wr << 6) + (m << 4) + (lane & 15);
          af[m] = *(const bf16x8*)(Ab + r * 128 + (slot << 4));
        }
        #pragma unroll
        for (int n = 0; n < 4; ++n) {
          const int r = (wc << 6) + (n << 4) + (lane & 15);
          bfr[n] = *(const bf16x8*)(Bb + r * 128 + (slot << 4));
        }
        #pragma unroll
        for (int m = 0; m < 4; ++m)
          #pragma unroll
          for (int n = 0; n < 4; ++n)
            acc[m][n] = __builtin_amdgcn_mfma_f32_16x16x32_bf16(af[m], bfr[n], acc[m][n], 0, 0, 0);
      }
    }
    __syncthreads();   // protect buffers before next stage
  }

  // ---- epilogue (atomic-free). C/D map: col=lane&15, row=(lane>>4)*4+reg.
  float* LF = (float*)As0;         // i-side sfull partials, 256 f32
  float* LM = LF + 256;            // i-side smask
  float* GF = LM + 256;            // j-side sfull
  float* GM = GF + 256;            // j-side smask

  float rnT_j[4];
  unsigned long long wj[4];        // mask bits row lab[j_n], i-span of this wave
  #pragma unroll
  for (int n = 0; n < 4; ++n) {
    const int j = j0 + (wc << 6) + (n << 4) + (lane & 15);
    rnT_j[n] = rnT[j];
    wj[n] = *(const unsigned long long*)(mbits + (size_t)lab[j] * MW + (i0 >> 5) + (wr << 1));
  }
  float pse[4] = {0.f, 0.f, 0.f, 0.f}, psm[4] = {0.f, 0.f, 0.f, 0.f};

  #pragma unroll
  for (int m = 0; m < 4; ++m) {
    #pragma unroll
    for (int r = 0; r < 4; ++r) {
      const int irow = (m << 4) + ((lane >> 4) << 2) + r;    // local row in wave's 64-span
      const int i = i0 + (wr << 6) + irow;
      const float rni = rnx[i];
      const unsigned long long wi =
          *(const unsigned long long*)(mbits + (size_t)lab[i] * MW + (j0 >> 5) + (wc << 1));
      float se = 0.f, sm = 0.f;
      #pragma unroll
      for (int n = 0; n < 4; ++n) {
        const int j = j0 + (wc << 6) + (n << 4) + (lane & 15);
        float e = __expf(acc[m][n][r] * rni * rnT_j[n]);
        if (i == j) e = 0.f;                                 // remove_diag
        se += e;
        const int bposj = (n << 4) + (lane & 15);            // j within wave's col-span
        sm += ((wi >> bposj) & 1ull) ? e : 0.f;
        pse[n] += e;
        psm[n] += ((wj[n] >> irow) & 1ull) ? e : 0.f;
      }
      #pragma unroll
      for (int off = 1; off < 16; off <<= 1) {
        se += __shfl_xor(se, off);
        sm += __shfl_xor(sm, off);
      }
      if ((lane & 15) == 0) {                                // lanes 0,16,32,48
        LF[(wc << 7) + (wr << 6) + irow] = se;
        LM[(wc << 7) + (wr << 6) + irow] = sm;
      }
    }
  }
  if (offdiag) {
    #pragma unroll
    for (int n = 0; n < 4; ++n) {
      float se = pse[n], sm = psm[n];
      se += __shfl_xor(se, 16); se += __shfl_xor(se, 32);
      sm += __shfl_xor(sm, 16); sm += __shfl_xor(sm, 32);
      if (lane < 16) {
        GF[(wr << 7) + (wc << 6) + (n << 4) + lane] = se;
        GM[(wr << 7) + (wc << 6) + (n << 4) + lane] = sm;
      }
    }
  }
  __syncthreads();

  // cross-wave combine + coalesced stores. Slot ownership:
  //   i-side (rows i0..i0+127) -> slot bx ; j-side (rows j0..j0+127) -> slot by.
  if (tid < 128) {
    scrF[(size_t)bx * NN + i0 + tid] = LF[tid] + LF[128 + tid];
    if (offdiag) scrF[(size_t)by * NN + j0 + tid] = GF[tid] + GF[128 + tid];
  } else {
    const int u = tid - 128;
    scrM[(size_t)bx * NN + i0 + u] = LM[u] + LM[128 + u];
    if (offdiag) scrM[(size_t)by * NN + j0 + u] = GM[u] + GM[128 + u];
  }
}

// ---------- kernel 3: loss = mean(log(den) - log(num)) ----------
__global__ __launch_bounds__(256) void k_final(
    const float* __restrict__ scrF, const float* __restrict__ scrM,
    const float* __restrict__ epos, float* __restrict__ out) {
  const int idx = blockIdx.x * 256 + threadIdx.x;
  float sf = 0.f, sm = 0.f;
  #pragma unroll
  for (int s = 0; s < SLOTS; ++s) {
    sf += scrF[(size_t)s * NN + idx];
    sm += scrM[(size_t)s * NN + idx];
  }
  const float ep  = epos[idx];
  const float num = sm + ep;
  const float den = ep + sf;
  float v = (logf(den) - logf(num)) * (1.0f / (float)NN);
  #pragma unroll
  for (int off = 32; off > 0; off >>= 1) v += __shfl_down(v, off);
  __shared__ float red[4];
  if ((threadIdx.x & 63) == 0) red[threadIdx.x >> 6] = v;
  __syncthreads();
  if (threadIdx.x == 0) atomicAdd(out, red[0] + red[1] + red[2] + red[3]);
}

extern "C" void kernel_launch(void* const* d_in, const int* in_sizes, int n_in,
                              void* d_out, int out_size, void* d_ws, size_t ws_size,
                              hipStream_t stream) {
  const float* X     = (const float*)d_in[0];
  const float* A     = (const float*)d_in[1];
  const int*   cmask = (const int*)d_in[2];
  const int*   lraw  = (const int*)d_in[3];
  const float* Tp    = (const float*)d_in[4];
  float* out = (float*)d_out;

  char* ws = (char*)d_ws;
  ushort* Xb   = (ushort*)ws;                          // 8 MB
  float* rnx   = (float*)(ws + (size_t)NN * DD * 2);
  float* rnT   = rnx + NN;
  float* epos  = rnT + NN;
  int*   lab   = (int*)(epos + NN);
  unsigned int* mbits = (unsigned int*)(lab + NN);     // 512 KB
  float* scrF  = (float*)(mbits + (size_t)NCLS * MW);  // 512 KB
  float* scrM  = scrF + (size_t)SLOTS * NN;            // 512 KB

  hipLaunchKernelGGL(k_pack,     dim3(NCLS * MW / 256 + NN / 256), dim3(256), 0, stream, cmask, lraw, mbits, lab);
  hipLaunchKernelGGL(k_rowstats, dim3(NN),    dim3(256), 0, stream, X, A, Tp, Xb, rnx, rnT, epos, out);
  hipLaunchKernelGGL(k_gram,     dim3(NTILE), dim3(256), 0, stream, Xb, rnx, rnT, lab, mbits, scrF, scrM);
  hipLaunchKernelGGL(k_final,    dim3(NN/256), dim3(256), 0, stream, scrF, scrM, epos, out);
}

// Round 14
// 79.527 us; speedup vs baseline: 1.1144x; 1.0218x over previous
//
#include <hip/hip_runtime.h>
#include <hip/hip_bf16.h>
#include <math.h>

// Conditional_Embedding_Contrastive_loss on MI355X (gfx950)
// R11: R10 (XCD map, BK=128, atomic-free epilogue) with 8-WAVE blocks (512 thr):
//      528 blocks x 2/CU -> 16 waves/CU (4/SIMD) — restores R4's wave-level
//      latency hiding (the invariant that actually set per-K-step rate).
//      Each wave owns a 64x32 sub-tile (acc 4x2).

#define NN   4096
#define DD   1024
#define NCLS 1000
#define EPSF 1e-8f
#define MW   (NN / 32)   // 128 mask words per class row
#define NTILE 528        // 32*33/2 upper-tri 128x128 tiles
#define SLOTS 32

typedef short bf16x8 __attribute__((ext_vector_type(8)));
typedef float f32x4  __attribute__((ext_vector_type(4)));

// ---------- kernel 0: bit-pack cls_mask + compact labels (fused) ----------
__global__ __launch_bounds__(256) void k_pack(const int* __restrict__ cmask,
                                              const int* __restrict__ lraw,
                                              unsigned int* __restrict__ mbits,
                                              int* __restrict__ lab) {
  const int b = blockIdx.x;
  if (b < NCLS * MW / 256) {             // 500 pack blocks
    const int wword = b * 256 + threadIdx.x;
    const int* src = cmask + (size_t)wword * 32;
    unsigned int v = 0;
    #pragma unroll
    for (int q = 0; q < 8; ++q) {
      const int4 c = *(const int4*)(src + q * 4);
      v |= (c.x != 0 ? 1u : 0u) << (q * 4 + 0);
      v |= (c.y != 0 ? 1u : 0u) << (q * 4 + 1);
      v |= (c.z != 0 ? 1u : 0u) << (q * 4 + 2);
      v |= (c.w != 0 ? 1u : 0u) << (q * 4 + 3);
    }
    mbits[wword] = v;
  } else {                                // 16 label blocks
    __shared__ int stride_s;
    if (threadIdx.x == 0) {
      int stride = 2;  // assume int64 (little-endian)
      #pragma unroll
      for (int t = 0; t < 8; ++t) {
        int lo = lraw[2 * t], hi = lraw[2 * t + 1];
        if (hi != 0 || (unsigned)lo >= (unsigned)NCLS) { stride = 1; break; }
      }
      stride_s = stride;
    }
    __syncthreads();
    const int i = (b - NCLS * MW / 256) * 256 + threadIdx.x;
    lab[i] = lraw[i * stride_s];
  }
}

// ---------- kernel 1: per-row norms, inst2embed_pos, f32->bf16 pack ----------
__global__ __launch_bounds__(256) void k_rowstats(
    const float* __restrict__ X, const float* __restrict__ A,
    const float* __restrict__ Tp, ushort* __restrict__ Xb,
    float* __restrict__ rnx, float* __restrict__ rnT,
    float* __restrict__ epos, float* __restrict__ out) {
  const int i = blockIdx.x;
  const int t = threadIdx.x;
  const size_t base = (size_t)i * DD + t * 4;
  const float4 xv = *(const float4*)(X + base);
  const float4 av = *(const float4*)(A + base);
  float sxx = xv.x * xv.x + xv.y * xv.y + xv.z * xv.z + xv.w * xv.w;
  float saa = av.x * av.x + av.y * av.y + av.z * av.z + av.w * av.w;
  float sxa = xv.x * av.x + xv.y * av.y + xv.z * av.z + xv.w * av.w;

  ushort4 pk;
  { __hip_bfloat16 b;
    b = __float2bfloat16(xv.x); pk.x = *(const ushort*)&b;
    b = __float2bfloat16(xv.y); pk.y = *(const ushort*)&b;
    b = __float2bfloat16(xv.z); pk.z = *(const ushort*)&b;
    b = __float2bfloat16(xv.w); pk.w = *(const ushort*)&b; }
  *(ushort4*)(Xb + base) = pk;

  #pragma unroll
  for (int off = 32; off > 0; off >>= 1) {
    sxx += __shfl_down(sxx, off);
    saa += __shfl_down(saa, off);
    sxa += __shfl_down(sxa, off);
  }
  __shared__ float red[3][4];
  const int w = t >> 6;
  if ((t & 63) == 0) { red[0][w] = sxx; red[1][w] = saa; red[2][w] = sxa; }
  __syncthreads();
  if (t == 0) {
    const float a  = red[0][0] + red[0][1] + red[0][2] + red[0][3];
    const float bb = red[1][0] + red[1][1] + red[1][2] + red[1][3];
    const float c  = red[2][0] + red[2][1] + red[2][2] + red[2][3];
    const float nxi = sqrtf(a), nai = sqrtf(bb);
    const float rT  = 1.0f / Tp[0];
    const float r   = 1.0f / fmaxf(nxi, 1e-20f);
    rnx[i] = r;
    rnT[i] = r * rT;
    epos[i] = expf((c / fmaxf(nxi * nai, EPSF)) * rT);
    if (i == 0) out[0] = 0.f;
  }
}

// ---------- kernel 2: symmetric fused Gram (128x128 tiles, BK=128, 8 waves) ----------
#define BM 128
#define BK 128
// LDS: 4 sub-buffers [128][64] bf16 (A-lo, A-hi, B-lo, B-hi), 16KB each.
// XOR swizzle within each: phys slot = logical ^ (row&7), pre-swizzled on the
// GLOBAL source since global_load_lds writes linearly.

__global__ __launch_bounds__(512, 4) void k_gram(
    const ushort* __restrict__ Xb, const float* __restrict__ rnx,
    const float* __restrict__ rnT,
    const int* __restrict__ lab, const unsigned int* __restrict__ mbits,
    float* __restrict__ scrF, float* __restrict__ scrM) {
  __shared__ __align__(16) char LDS[4 * BM * 64 * 2];   // 64 KB
  char* As0 = LDS;                 // A k-lo
  char* As1 = LDS + 16384;         // A k-hi
  char* Bs0 = LDS + 32768;         // B k-lo
  char* Bs1 = LDS + 49152;         // B k-hi
  const int tid  = threadIdx.x;
  const int lane = tid & 63;
  const int w    = tid >> 6;       // wave 0..7
  const int wr   = w >> 2;         // 0..1 : 64-row half
  const int wc   = w & 3;          // 0..3 : 32-col quarter

  // XCD-aware tile decode: xcd = blk%8 owns row-pairs {2x, 2x+1}; each pair
  // p covers rows {p, 31-p} with exactly 33 tiles.
  const int xcd = blockIdx.x & 7;
  const int l   = blockIdx.x >> 3;          // 0..65
  const int p   = (xcd << 1) + (l >= 33);   // pair index
  const int q   = (l >= 33) ? (l - 33) : l; // 0..32 within pair
  int by, bx;
  if (q < 32 - p) { by = p;      bx = p + q; }
  else            { by = 31 - p; bx = 31 - p + (q - (32 - p)); }
  const bool offdiag = (bx != by);
  const int i0 = by * BM;
  const int j0 = bx * BM;

  const int sslot = (lane & 7) ^ (lane >> 3);  // pre-swizzled global k-slot

  f32x4 acc[4][2];
  #pragma unroll
  for (int m = 0; m < 4; ++m)
    #pragma unroll
    for (int n = 0; n < 2; ++n)
      acc[m][n] = (f32x4){0.f, 0.f, 0.f, 0.f};

  // staging: wave w covers rows [w*16, w*16+16) of both A and B; 2 chunks each.
  const ushort* pA[2];
  const ushort* pB[2];
  #pragma unroll
  for (int q2 = 0; q2 < 2; ++q2) {
    const int row = (w << 4) + (q2 << 3) + (lane >> 3);
    pA[q2] = Xb + (size_t)(i0 + row) * DD + sslot * 8;
    pB[q2] = Xb + (size_t)(j0 + row) * DD + sslot * 8;
  }

  for (int k0 = 0; k0 < DD; k0 += BK) {
    #pragma unroll
    for (int q2 = 0; q2 < 2; ++q2) {
      const int ldo = ((w << 1) + q2) * 1024;
      __builtin_amdgcn_global_load_lds(
          (const __attribute__((address_space(1))) void*)(pA[q2] + k0),
          (__attribute__((address_space(3))) void*)(As0 + ldo), 16, 0, 0);
      __builtin_amdgcn_global_load_lds(
          (const __attribute__((address_space(1))) void*)(pA[q2] + k0 + 64),
          (__attribute__((address_space(3))) void*)(As1 + ldo), 16, 0, 0);
      __builtin_amdgcn_global_load_lds(
          (const __attribute__((address_space(1))) void*)(pB[q2] + k0),
          (__attribute__((address_space(3))) void*)(Bs0 + ldo), 16, 0, 0);
      __builtin_amdgcn_global_load_lds(
          (const __attribute__((address_space(1))) void*)(pB[q2] + k0 + 64),
          (__attribute__((address_space(3))) void*)(Bs1 + ldo), 16, 0, 0);
    }
    __syncthreads();   // single vmcnt drain per 128-K

    #pragma unroll
    for (int kh = 0; kh < 2; ++kh) {
      const char* Ab = kh ? As1 : As0;
      const char* Bb = kh ? Bs1 : Bs0;
      #pragma unroll
      for (int ks = 0; ks < 2; ++ks) {
        const int slot = ((ks << 2) + (lane >> 4)) ^ (lane & 7);
        bf16x8 af[4], bfr[2];
        #pragma unroll
        for (int m = 0; m < 4; ++m) {
          const int r = (wr << 6) + (m << 4) + (lane & 15);
          af[m] = *(const bf16x8*)(Ab + r * 128 + (slot << 4));
        }
        #pragma unroll
        for (int n = 0; n < 2; ++n) {
          const int r = (wc << 5) + (n << 4) + (lane & 15);
          bfr[n] = *(const bf16x8*)(Bb + r * 128 + (slot << 4));
        }
        #pragma unroll
        for (int m = 0; m < 4; ++m)
          #pragma unroll
          for (int n = 0; n < 2; ++n)
            acc[m][n] = __builtin_amdgcn_mfma_f32_16x16x32_bf16(af[m], bfr[n], acc[m][n], 0, 0, 0);
      }
    }
    __syncthreads();   // protect buffers before next stage
  }

  // ---- epilogue (atomic-free). C/D map: col=lane&15, row=(lane>>4)*4+reg.
  // Wave sub-tile: rows [wr*64, wr*64+64), cols [wc*32, wc*32+32).
  float* LF = (float*)LDS;         // i-side sfull partials [wc][wr][64] = 512
  float* LM = LF + 512;            // i-side smask
  float* GF = LM + 512;            // j-side sfull [wr][128] = 256
  float* GM = GF + 256;            // j-side smask

  float rnT_j[2];
  unsigned long long wj[2];        // mask row lab[j_n], 64 bits over wave's i-span
  #pragma unroll
  for (int n = 0; n < 2; ++n) {
    const int j = j0 + (wc << 5) + (n << 4) + (lane & 15);
    rnT_j[n] = rnT[j];
    wj[n] = *(const unsigned long long*)(mbits + (size_t)lab[j] * MW + (i0 >> 5) + (wr << 1));
  }
  float pse[2] = {0.f, 0.f}, psm[2] = {0.f, 0.f};

  #pragma unroll
  for (int m = 0; m < 4; ++m) {
    #pragma unroll
    for (int r = 0; r < 4; ++r) {
      const int irow = (m << 4) + ((lane >> 4) << 2) + r;    // 0..63 in wave's row-half
      const int i = i0 + (wr << 6) + irow;
      const float rni = rnx[i];
      const unsigned int wi = mbits[(size_t)lab[i] * MW + (j0 >> 5) + wc];  // 32 bits, wave's col-span
      float se = 0.f, sm = 0.f;
      #pragma unroll
      for (int n = 0; n < 2; ++n) {
        const int j = j0 + (wc << 5) + (n << 4) + (lane & 15);
        float e = __expf(acc[m][n][r] * rni * rnT_j[n]);
        if (i == j) e = 0.f;                                 // remove_diag
        se += e;
        const int bposj = (n << 4) + (lane & 15);            // 0..31
        sm += ((wi >> bposj) & 1u) ? e : 0.f;
        pse[n] += e;
        psm[n] += ((wj[n] >> irow) & 1ull) ? e : 0.f;
      }
      #pragma unroll
      for (int off = 1; off < 16; off <<= 1) {
        se += __shfl_xor(se, off);
        sm += __shfl_xor(sm, off);
      }
      if ((lane & 15) == 0) {                                // lanes 0,16,32,48
        LF[(wc << 7) + (wr << 6) + irow] = se;
        LM[(wc << 7) + (wr << 6) + irow] = sm;
      }
    }
  }
  if (offdiag) {
    #pragma unroll
    for (int n = 0; n < 2; ++n) {
      float se = pse[n], sm = psm[n];
      se += __shfl_xor(se, 16); se += __shfl_xor(se, 32);
      sm += __shfl_xor(sm, 16); sm += __shfl_xor(sm, 32);
      if (lane < 16) {
        GF[(wr << 7) + (wc << 5) + (n << 4) + lane] = se;
        GM[(wr << 7) + (wc << 5) + (n << 4) + lane] = sm;
      }
    }
  }
  __syncthreads();

  // cross-wave combine + coalesced stores. Slot ownership:
  //   i-side (rows i0..i0+127) -> slot bx ; j-side (rows j0..j0+127) -> slot by.
  if (tid < 128) {
    scrF[(size_t)bx * NN + i0 + tid] = LF[tid] + LF[128 + tid] + LF[256 + tid] + LF[384 + tid];
    if (offdiag) scrF[(size_t)by * NN + j0 + tid] = GF[tid] + GF[128 + tid];
  } else if (tid < 256) {
    const int u = tid - 128;
    scrM[(size_t)bx * NN + i0 + u] = LM[u] + LM[128 + u] + LM[256 + u] + LM[384 + u];
    if (offdiag) scrM[(size_t)by * NN + j0 + u] = GM[u] + GM[128 + u];
  }
}

// ---------- kernel 3: loss = mean(log(den) - log(num)) ----------
__global__ __launch_bounds__(256) void k_final(
    const float* __restrict__ scrF, const float* __restrict__ scrM,
    const float* __restrict__ epos, float* __restrict__ out) {
  const int idx = blockIdx.x * 256 + threadIdx.x;
  float sf = 0.f, sm = 0.f;
  #pragma unroll
  for (int s = 0; s < SLOTS; ++s) {
    sf += scrF[(size_t)s * NN + idx];
    sm += scrM[(size_t)s * NN + idx];
  }
  const float ep  = epos[idx];
  const float num = sm + ep;
  const float den = ep + sf;
  float v = (logf(den) - logf(num)) * (1.0f / (float)NN);
  #pragma unroll
  for (int off = 32; off > 0; off >>= 1) v += __shfl_down(v, off);
  __shared__ float red[4];
  if ((threadIdx.x & 63) == 0) red[threadIdx.x >> 6] = v;
  __syncthreads();
  if (threadIdx.x == 0) atomicAdd(out, red[0] + red[1] + red[2] + red[3]);
}

extern "C" void kernel_launch(void* const* d_in, const int* in_sizes, int n_in,
                              void* d_out, int out_size, void* d_ws, size_t ws_size,
                              hipStream_t stream) {
  const float* X     = (const float*)d_in[0];
  const float* A     = (const float*)d_in[1];
  const int*   cmask = (const int*)d_in[2];
  const int*   lraw  = (const int*)d_in[3];
  const float* Tp    = (const float*)d_in[4];
  float* out = (float*)d_out;

  char* ws = (char*)d_ws;
  ushort* Xb   = (ushort*)ws;                          // 8 MB
  float* rnx   = (float*)(ws + (size_t)NN * DD * 2);
  float* rnT   = rnx + NN;
  float* epos  = rnT + NN;
  int*   lab   = (int*)(epos + NN);
  unsigned int* mbits = (unsigned int*)(lab + NN);     // 512 KB
  float* scrF  = (float*)(mbits + (size_t)NCLS * MW);  // 512 KB
  float* scrM  = scrF + (size_t)SLOTS * NN;            // 512 KB

  hipLaunchKernelGGL(k_pack,     dim3(NCLS * MW / 256 + NN / 256), dim3(256), 0, stream, cmask, lraw, mbits, lab);
  hipLaunchKernelGGL(k_rowstats, dim3(NN),     dim3(256), 0, stream, X, A, Tp, Xb, rnx, rnT, epos, out);
  hipLaunchKernelGGL(k_gram,     dim3(NTILE),  dim3(512), 0, stream, Xb, rnx, rnT, lab, mbits, scrF, scrM);
  hipLaunchKernelGGL(k_final,    dim3(NN/256), dim3(256), 0, stream, scrF, scrM, epos, out);
}